// Round 1
// baseline (4113.340 us; speedup 1.0000x reference)
//
#include <hip/hip_runtime.h>
#include <math.h>

namespace {
constexpr int kN = 16384;
constexpr int kD = 2048;
constexpr int kH = 4096;
constexpr int kE = 64;
constexpr int kShared = 8;

// d_out layout (floats), reference return order
constexpr int OFF_GW = 0;                       // global_weights: N x 8
constexpr int OFF_LW = kN * kShared;            // local_weights:  N x 2  (131072)
constexpr int OFF_LI = OFF_LW + kN * 2;         // local_indices:  N x 2  (163840, as float)
constexpr int OFF_W  = OFF_LI + kN * 2;         // weights:        N x 64 (196608) -- doubles as logit accumulator

constexpr int BM = 128;     // rows per block
constexpr int BN = 128;     // H-cols per chunk
constexpr int BK = 32;      // K tile
constexpr int HSPLIT = 4;   // H split across blocks (atomic logit accumulation)
constexpr int HRANGE = kH / HSPLIT;   // 1024
constexpr int CHUNKS = HRANGE / BN;   // 8
constexpr int GS_STRIDE = 132;        // padded stride for g^T LDS tile (bank-conflict relief)
}

// ---------------------------------------------------------------------------
// Kernel 1: fused  h = gelu(x@W1 + b1)  and  logits += h@W2   (fp32 vector)
// grid = 512 (128 row-blocks x 4 H-splits), block = 256
// ---------------------------------------------------------------------------
__global__ __launch_bounds__(256, 2)
void gemm1_kernel(const float* __restrict__ x, const float* __restrict__ W1,
                  const float* __restrict__ b1, const float* __restrict__ W2,
                  float* __restrict__ logits)
{
    // smem: staging (As 32x128 + Bs 32x128 = 8192 floats) unioned with g^T (64x132 = 8448)
    __shared__ __align__(16) float smem[64 * GS_STRIDE];
    float* As = smem;            // [BK][BM], k-major (m contiguous)
    float* Bs = smem + BK * BM;  // [BK][BN], k-major (n contiguous)
    float* gS = smem;            // [64 h][GS_STRIDE] : g transposed, r contiguous

    const int t  = threadIdx.x;
    const int bx = blockIdx.x;
    const int rowBlock = bx >> 2;
    const int hSplit   = bx & 3;
    const int rowBase  = rowBlock * BM;
    const int hBase0   = hSplit * HRANGE;

    const int ty = t >> 4;           // 0..15
    const int tx = t & 15;           // 0..15
    const int r0 = ty * 8;           // this thread's 8 rows in the tile
    const int c0 = tx * 8;           // this thread's 8 H-cols in the tile

    // GEMM2 mapping: 4 rows x 8 experts per thread
    const int g_r0 = (t >> 3) * 4;   // 0..124
    const int g_e0 = (t & 7) * 8;    // 0..56

    float lacc[4][8];
    #pragma unroll
    for (int i = 0; i < 4; ++i)
        #pragma unroll
        for (int j = 0; j < 8; ++j) lacc[i][j] = 0.0f;

    for (int chunk = 0; chunk < CHUNKS; ++chunk) {
        const int hBase = hBase0 + chunk * BN;

        float C[8][8];
        #pragma unroll
        for (int i = 0; i < 8; ++i)
            #pragma unroll
            for (int j = 0; j < 8; ++j) C[i][j] = 0.0f;

        for (int kt = 0; kt < kD; kt += BK) {
            __syncthreads();
            // --- stage A: As[k][m] = x[rowBase+m][kt+k]  (transpose during staging)
            #pragma unroll
            for (int i = 0; i < 4; ++i) {
                const int f  = t + 256 * i;        // 0..1023 float4 slots
                const int m  = f >> 3;             // 0..127
                const int kq = (f & 7) * 4;        // 0,4,...,28
                const float4 v = *reinterpret_cast<const float4*>(
                    x + (size_t)(rowBase + m) * kD + kt + kq);
                As[(kq + 0) * BM + m] = v.x;
                As[(kq + 1) * BM + m] = v.y;
                As[(kq + 2) * BM + m] = v.z;
                As[(kq + 3) * BM + m] = v.w;
            }
            // --- stage B: Bs[k][n] = W1[kt+k][hBase+n]  (natural layout, float4)
            #pragma unroll
            for (int i = 0; i < 4; ++i) {
                const int f  = t + 256 * i;
                const int k  = f >> 5;             // 0..31
                const int n4 = (f & 31) * 4;       // 0..124
                *reinterpret_cast<float4*>(Bs + k * BN + n4) =
                    *reinterpret_cast<const float4*>(W1 + (size_t)(kt + k) * kH + hBase + n4);
            }
            __syncthreads();

            // --- inner: 32 k-steps, 64 FMA each
            #pragma unroll 8
            for (int k = 0; k < BK; ++k) {
                const float4 a0 = *reinterpret_cast<const float4*>(As + k * BM + r0);
                const float4 a1 = *reinterpret_cast<const float4*>(As + k * BM + r0 + 4);
                const float4 b0 = *reinterpret_cast<const float4*>(Bs + k * BN + c0);
                const float4 b1v = *reinterpret_cast<const float4*>(Bs + k * BN + c0 + 4);
                const float a[8] = {a0.x, a0.y, a0.z, a0.w, a1.x, a1.y, a1.z, a1.w};
                const float b[8] = {b0.x, b0.y, b0.z, b0.w, b1v.x, b1v.y, b1v.z, b1v.w};
                #pragma unroll
                for (int i = 0; i < 8; ++i)
                    #pragma unroll
                    for (int j = 0; j < 8; ++j)
                        C[i][j] = fmaf(a[i], b[j], C[i][j]);
            }
        }

        // --- bias + exact gelu (in registers)
        #pragma unroll
        for (int j = 0; j < 8; ++j) {
            const float bb = b1[hBase + c0 + j];
            #pragma unroll
            for (int i = 0; i < 8; ++i) {
                const float hv = C[i][j] + bb;
                C[i][j] = 0.5f * hv * (1.0f + erff(hv * 0.70710678118654752f));
            }
        }

        // --- fused GEMM2 partial: logits[r][e] += sum_h g[r][h] * W2[hBase+h][e]
        // two halves of 64 h-cols each, g^T round-tripped through LDS
        for (int half = 0; half < 2; ++half) {
            __syncthreads();   // previous smem users done
            if ((tx >> 3) == half) {
                const int hloc0 = c0 - half * 64;   // 0..56
                #pragma unroll
                for (int j = 0; j < 8; ++j) {
                    const float4 col = make_float4(C[0][j], C[1][j], C[2][j], C[3][j]);
                    const float4 col2 = make_float4(C[4][j], C[5][j], C[6][j], C[7][j]);
                    *reinterpret_cast<float4*>(gS + (hloc0 + j) * GS_STRIDE + r0)     = col;
                    *reinterpret_cast<float4*>(gS + (hloc0 + j) * GS_STRIDE + r0 + 4) = col2;
                }
            }
            __syncthreads();
            const float* W2p = W2 + (size_t)(hBase + half * 64) * kE + g_e0;
            #pragma unroll 4
            for (int h = 0; h < 64; ++h) {
                const float4 gv = *reinterpret_cast<const float4*>(gS + h * GS_STRIDE + g_r0);
                const float4 w0 = *reinterpret_cast<const float4*>(W2p + (size_t)h * kE);
                const float4 w1 = *reinterpret_cast<const float4*>(W2p + (size_t)h * kE + 4);
                const float ga[4] = {gv.x, gv.y, gv.z, gv.w};
                const float wb[8] = {w0.x, w0.y, w0.z, w0.w, w1.x, w1.y, w1.z, w1.w};
                #pragma unroll
                for (int i = 0; i < 4; ++i)
                    #pragma unroll
                    for (int j = 0; j < 8; ++j)
                        lacc[i][j] = fmaf(ga[i], wb[j], lacc[i][j]);
            }
        }
    }

    // --- one atomicAdd per logit element per block (4 H-split contributors)
    #pragma unroll
    for (int i = 0; i < 4; ++i)
        #pragma unroll
        for (int j = 0; j < 8; ++j)
            atomicAdd(logits + (size_t)(rowBase + g_r0 + i) * kE + g_e0 + j, lacc[i][j]);
}

// ---------------------------------------------------------------------------
// Kernel 2: per-row (one wave each): +b2, softmax in place, global weights,
// top-2 over local with jax min-index tie-break, indices written as float.
// ---------------------------------------------------------------------------
__global__ __launch_bounds__(256)
void router_kernel(const float* __restrict__ b2, float* __restrict__ out)
{
    const int lane = threadIdx.x & 63;
    const int row  = blockIdx.x * 4 + (threadIdx.x >> 6);

    float* wrow = out + OFF_W + (size_t)row * kE;
    const float logit = wrow[lane] + b2[lane];

    // softmax (64-lane shuffle reductions)
    float m = logit;
    #pragma unroll
    for (int off = 32; off > 0; off >>= 1) m = fmaxf(m, __shfl_xor(m, off));
    const float p = expf(logit - m);
    float s = p;
    #pragma unroll
    for (int off = 32; off > 0; off >>= 1) s += __shfl_xor(s, off);
    const float w = p / s;

    wrow[lane] = w;                                     // weights (in place over logits)
    if (lane < kShared) out[OFF_GW + (size_t)row * kShared + lane] = w;

    // top-1 over local lanes (8..63), min-index on ties
    float v1 = (lane >= kShared) ? w : -1.0f;
    int   i1 = lane - kShared;
    #pragma unroll
    for (int off = 32; off > 0; off >>= 1) {
        const float ov = __shfl_xor(v1, off);
        const int   oi = __shfl_xor(i1, off);
        if (ov > v1 || (ov == v1 && oi < i1)) { v1 = ov; i1 = oi; }
    }
    // top-2: exclude winner index
    float v2 = (lane >= kShared && (lane - kShared) != i1) ? w : -1.0f;
    int   i2 = lane - kShared;
    #pragma unroll
    for (int off = 32; off > 0; off >>= 1) {
        const float ov = __shfl_xor(v2, off);
        const int   oi = __shfl_xor(i2, off);
        if (ov > v2 || (ov == v2 && oi < i2)) { v2 = ov; i2 = oi; }
    }
    if (lane == 0) {
        out[OFF_LW + (size_t)row * 2 + 0] = v1;
        out[OFF_LW + (size_t)row * 2 + 1] = v2;
        out[OFF_LI + (size_t)row * 2 + 0] = (float)i1;
        out[OFF_LI + (size_t)row * 2 + 1] = (float)i2;
    }
}

extern "C" void kernel_launch(void* const* d_in, const int* in_sizes, int n_in,
                              void* d_out, int out_size, void* d_ws, size_t ws_size,
                              hipStream_t stream)
{
    const float* x  = (const float*)d_in[0];
    const float* W1 = (const float*)d_in[1];
    const float* b1 = (const float*)d_in[2];
    const float* W2 = (const float*)d_in[3];
    const float* b2 = (const float*)d_in[4];
    float* out = (float*)d_out;
    float* logits = out + OFF_W;   // weights region doubles as logit accumulator

    hipMemsetAsync(logits, 0, (size_t)kN * kE * sizeof(float), stream);
    hipLaunchKernelGGL(gemm1_kernel, dim3((kN / BM) * HSPLIT), dim3(256), 0, stream,
                       x, W1, b1, W2, logits);
    hipLaunchKernelGGL(router_kernel, dim3(kN / 4), dim3(256), 0, stream, b2, out);
}

// Round 2
// 1787.584 us; speedup vs baseline: 2.3011x; 2.3011x over previous
//
#include <hip/hip_runtime.h>
#include <math.h>

namespace {
constexpr int kN = 16384;
constexpr int kD = 2048;
constexpr int kH = 4096;
constexpr int kE = 64;
constexpr int kShared = 8;

// d_out layout (floats), reference return order
constexpr int OFF_GW = 0;                       // global_weights: N x 8
constexpr int OFF_LW = kN * kShared;            // local_weights:  N x 2
constexpr int OFF_LI = OFF_LW + kN * 2;         // local_indices:  N x 2 (as float)
constexpr int OFF_W  = OFF_LI + kN * 2;         // weights: N x 64 -- doubles as logit accumulator

constexpr int GS_STRIDE = 132;

// fast-path workspace layout (f16 elements)
constexpr size_t XH_OFF  = 0;
constexpr size_t XL_OFF  = (size_t)kN * kD;                 // 33.5M
constexpr size_t W1TH_OFF = XL_OFF + (size_t)kN * kD;       // 67.1M
constexpr size_t W1TL_OFF = W1TH_OFF + (size_t)kH * kD;     // 75.5M
constexpr size_t WS_NEEDED = (W1TL_OFF + (size_t)kH * kD) * 2;  // bytes = 167,772,160
}

typedef _Float16 half8  __attribute__((ext_vector_type(8)));
typedef _Float16 half4t __attribute__((ext_vector_type(4)));
typedef float    f32x16 __attribute__((ext_vector_type(16)));

__device__ __forceinline__ void async16(const _Float16* g, _Float16* l) {
    __builtin_amdgcn_global_load_lds(
        (const __attribute__((address_space(1))) void*)g,
        (__attribute__((address_space(3))) void*)l, 16, 0, 0);
}

// ---------------------------------------------------------------------------
// Pre-pass 1: x (fp32) -> xh, xl (f16 planes; xl pre-scaled by 2048)
// ---------------------------------------------------------------------------
__global__ __launch_bounds__(256)
void convert_x(const float* __restrict__ x, _Float16* __restrict__ xh,
               _Float16* __restrict__ xl)
{
    const size_t i = ((size_t)blockIdx.x * 256 + threadIdx.x) * 4;
    const float4 v = *reinterpret_cast<const float4*>(x + i);
    half4t h, l;
    const float vs[4] = {v.x, v.y, v.z, v.w};
    #pragma unroll
    for (int j = 0; j < 4; ++j) {
        const _Float16 hj = (_Float16)vs[j];
        h[j] = hj;
        l[j] = (_Float16)((vs[j] - (float)hj) * 2048.0f);
    }
    *reinterpret_cast<half4t*>(xh + i) = h;
    *reinterpret_cast<half4t*>(xl + i) = l;
}

// ---------------------------------------------------------------------------
// Pre-pass 2: W1 [D][H] fp32 -> W1^T hi/lo planes [H][D] f16 (lo scaled 2048)
// ---------------------------------------------------------------------------
__global__ __launch_bounds__(256)
void convert_w1t(const float* __restrict__ W1, _Float16* __restrict__ th,
                 _Float16* __restrict__ tl)
{
    __shared__ float T[64][65];
    const int bk = blockIdx.x & 31;   // 32 k-tiles (D/64)
    const int bn = blockIdx.x >> 5;   // 64 n-tiles (H/64)
    const int k0 = bk * 64, n0 = bn * 64;
    const int t = threadIdx.x;
    const int c4 = (t & 15) * 4, r = t >> 4;

    #pragma unroll
    for (int i = 0; i < 4; ++i) {
        const int kk = r + 16 * i;
        const float4 v = *reinterpret_cast<const float4*>(
            W1 + (size_t)(k0 + kk) * kH + n0 + c4);
        T[kk][c4 + 0] = v.x; T[kk][c4 + 1] = v.y;
        T[kk][c4 + 2] = v.z; T[kk][c4 + 3] = v.w;
    }
    __syncthreads();
    #pragma unroll
    for (int i = 0; i < 4; ++i) {
        const int nn = r + 16 * i;
        half4t h, l;
        #pragma unroll
        for (int j = 0; j < 4; ++j) {
            const float vv = T[c4 + j][nn];
            const _Float16 hj = (_Float16)vv;
            h[j] = hj;
            l[j] = (_Float16)((vv - (float)hj) * 2048.0f);
        }
        *reinterpret_cast<half4t*>(th + (size_t)(n0 + nn) * kD + k0 + c4) = h;
        *reinterpret_cast<half4t*>(tl + (size_t)(n0 + nn) * kD + k0 + c4) = l;
    }
}

// ---------------------------------------------------------------------------
// Fast GEMM1: split-f16 3-pass MFMA  C = x@W1 (fp32-grade), fused gelu + GEMM2
// grid = 4096 (128 m-blocks x 32 n-panels, XCD-swizzled), block = 256 (4 waves)
// ---------------------------------------------------------------------------
__global__ __launch_bounds__(256, 2)
void gemm1_mfma(const _Float16* __restrict__ xh, const _Float16* __restrict__ xl,
                const _Float16* __restrict__ w1th, const _Float16* __restrict__ w1tl,
                const float* __restrict__ b1, const float* __restrict__ W2,
                float* __restrict__ logits)
{
    // union: staging 32 KB (Ah|Al|Bh|Bl, each 128 rows x 32 f16) / gS 64x132 f32
    __shared__ __align__(16) float smem[64 * GS_STRIDE];
    _Float16* lds = (_Float16*)smem;
    float* gS = smem;

    const int t = threadIdx.x;
    const int lane = t & 63;
    const int w = t >> 6;
    const int bx = blockIdx.x;
    const int mBlock = (bx >> 3) >> 2;
    const int nPanel = ((bx & 7) << 2) | ((bx >> 3) & 3);
    const int rowBase = mBlock * 128;
    const int hBase = nPanel * 128;

    const int mw = (w >> 1) * 64, nw = (w & 1) * 64;

    // --- precompute staging source offsets (relative to xh, f16 elements)
    unsigned int gofs[8];
    #pragma unroll
    for (int i = 0; i < 8; ++i) {
        const int c = i * 256 + t;          // chunk id 0..2047 (16 B each)
        const int tile = c >> 9;            // 0:Ah 1:Al 2:Bh 3:Bl
        const int cc = c & 511;
        const int row = cc >> 2, q = cc & 3;
        const unsigned int plane =
            (tile == 0) ? (unsigned int)XH_OFF :
            (tile == 1) ? (unsigned int)XL_OFF :
            (tile == 2) ? (unsigned int)W1TH_OFF : (unsigned int)W1TL_OFF;
        const int rbase = (tile < 2) ? rowBase : hBase;
        gofs[i] = plane + (unsigned int)(rbase + row) * kD + q * 8;
    }

    // --- frag LDS byte offsets (f16 elements), kt-invariant
    const int lq = (lane >> 5) * 8;   // k sub-offset within 16-k step
    int aOff[2], bOff[2];
    #pragma unroll
    for (int mt = 0; mt < 2; ++mt)
        aOff[mt] = (mw + mt * 32 + (lane & 31)) * 32 + lq;
    #pragma unroll
    for (int nt = 0; nt < 2; ++nt)
        bOff[nt] = (nw + nt * 32 + (lane & 31)) * 32 + lq;

    f32x16 accH[2][2], accL[2][2];
    #pragma unroll
    for (int a = 0; a < 2; ++a)
        #pragma unroll
        for (int b = 0; b < 2; ++b)
            #pragma unroll
            for (int r = 0; r < 16; ++r) { accH[a][b][r] = 0.0f; accL[a][b][r] = 0.0f; }

    for (int kt = 0; kt < kD; kt += 32) {
        __syncthreads();
        #pragma unroll
        for (int i = 0; i < 8; ++i)
            async16(xh + gofs[i] + kt, lds + ((i * 256 + t) * 8));
        __syncthreads();

        half8 aH[2][2], aL[2][2], bH[2][2], bL[2][2];
        #pragma unroll
        for (int mt = 0; mt < 2; ++mt)
            #pragma unroll
            for (int ks = 0; ks < 2; ++ks) {
                aH[mt][ks] = *reinterpret_cast<const half8*>(lds + aOff[mt] + ks * 16);
                aL[mt][ks] = *reinterpret_cast<const half8*>(lds + 4096 + aOff[mt] + ks * 16);
            }
        #pragma unroll
        for (int nt = 0; nt < 2; ++nt)
            #pragma unroll
            for (int ks = 0; ks < 2; ++ks) {
                bH[nt][ks] = *reinterpret_cast<const half8*>(lds + 8192 + bOff[nt] + ks * 16);
                bL[nt][ks] = *reinterpret_cast<const half8*>(lds + 12288 + bOff[nt] + ks * 16);
            }

        #pragma unroll
        for (int ks = 0; ks < 2; ++ks)
            #pragma unroll
            for (int mt = 0; mt < 2; ++mt)
                #pragma unroll
                for (int nt = 0; nt < 2; ++nt) {
                    accH[mt][nt] = __builtin_amdgcn_mfma_f32_32x32x16_f16(
                        aH[mt][ks], bH[nt][ks], accH[mt][nt], 0, 0, 0);
                    accL[mt][nt] = __builtin_amdgcn_mfma_f32_32x32x16_f16(
                        aH[mt][ks], bL[nt][ks], accL[mt][nt], 0, 0, 0);
                    accL[mt][nt] = __builtin_amdgcn_mfma_f32_32x32x16_f16(
                        aL[mt][ks], bH[nt][ks], accL[mt][nt], 0, 0, 0);
                }
    }

    // --- epilogue: combine, bias, gelu -> gS (g^T), fused GEMM2 partial
    const float inv2048 = 1.0f / 2048.0f;
    const int g_r0 = (t >> 3) * 4;
    const int g_e0 = (t & 7) * 8;
    float lacc[4][8];
    #pragma unroll
    for (int i = 0; i < 4; ++i)
        #pragma unroll
        for (int j = 0; j < 8; ++j) lacc[i][j] = 0.0f;

    for (int hf = 0; hf < 2; ++hf) {
        __syncthreads();
        if ((w & 1) == hf) {
            #pragma unroll
            for (int nt = 0; nt < 2; ++nt) {
                const int hl = nt * 32 + (lane & 31);
                const float bb = b1[hBase + hf * 64 + hl];
                #pragma unroll
                for (int mt = 0; mt < 2; ++mt) {
                    #pragma unroll
                    for (int rq = 0; rq < 4; ++rq) {
                        float vr[4];
                        #pragma unroll
                        for (int rr = 0; rr < 4; ++rr) {
                            const int r = rq * 4 + rr;
                            const float hv = accH[mt][nt][r] + accL[mt][nt][r] * inv2048 + bb;
                            vr[rr] = 0.5f * hv * (1.0f + erff(hv * 0.70710678118654752f));
                        }
                        const int mrow = mw + mt * 32 + 8 * rq + 4 * (lane >> 5);
                        *reinterpret_cast<float4*>(gS + hl * GS_STRIDE + mrow) =
                            make_float4(vr[0], vr[1], vr[2], vr[3]);
                    }
                }
            }
        }
        __syncthreads();
        const float* W2p = W2 + (size_t)(hBase + hf * 64) * kE + g_e0;
        #pragma unroll 4
        for (int h = 0; h < 64; ++h) {
            const float4 gv = *reinterpret_cast<const float4*>(gS + h * GS_STRIDE + g_r0);
            const float4 w0 = *reinterpret_cast<const float4*>(W2p + (size_t)h * kE);
            const float4 w1 = *reinterpret_cast<const float4*>(W2p + (size_t)h * kE + 4);
            const float ga[4] = {gv.x, gv.y, gv.z, gv.w};
            const float wb[8] = {w0.x, w0.y, w0.z, w0.w, w1.x, w1.y, w1.z, w1.w};
            #pragma unroll
            for (int i = 0; i < 4; ++i)
                #pragma unroll
                for (int j = 0; j < 8; ++j)
                    lacc[i][j] = fmaf(ga[i], wb[j], lacc[i][j]);
        }
    }

    #pragma unroll
    for (int i = 0; i < 4; ++i)
        #pragma unroll
        for (int j = 0; j < 8; ++j)
            atomicAdd(logits + (size_t)(rowBase + g_r0 + i) * kE + g_e0 + j, lacc[i][j]);
}

// ---------------------------------------------------------------------------
// Fallback fp32 GEMM1 (verified R1 kernel) — used when ws is too small
// ---------------------------------------------------------------------------
__global__ __launch_bounds__(256, 2)
void gemm1_kernel(const float* __restrict__ x, const float* __restrict__ W1,
                  const float* __restrict__ b1, const float* __restrict__ W2,
                  float* __restrict__ logits)
{
    __shared__ __align__(16) float smem[64 * GS_STRIDE];
    float* As = smem;
    float* Bs = smem + 32 * 128;
    float* gS = smem;

    const int t  = threadIdx.x;
    const int bx = blockIdx.x;
    const int rowBlock = bx >> 2;
    const int hSplit   = bx & 3;
    const int rowBase  = rowBlock * 128;
    const int hBase0   = hSplit * 1024;

    const int ty = t >> 4;
    const int tx = t & 15;
    const int r0 = ty * 8;
    const int c0 = tx * 8;
    const int g_r0 = (t >> 3) * 4;
    const int g_e0 = (t & 7) * 8;

    float lacc[4][8];
    #pragma unroll
    for (int i = 0; i < 4; ++i)
        #pragma unroll
        for (int j = 0; j < 8; ++j) lacc[i][j] = 0.0f;

    for (int chunk = 0; chunk < 8; ++chunk) {
        const int hBase = hBase0 + chunk * 128;
        float C[8][8];
        #pragma unroll
        for (int i = 0; i < 8; ++i)
            #pragma unroll
            for (int j = 0; j < 8; ++j) C[i][j] = 0.0f;

        for (int kt = 0; kt < kD; kt += 32) {
            __syncthreads();
            #pragma unroll
            for (int i = 0; i < 4; ++i) {
                const int f  = t + 256 * i;
                const int m  = f >> 3;
                const int kq = (f & 7) * 4;
                const float4 v = *reinterpret_cast<const float4*>(
                    x + (size_t)(rowBase + m) * kD + kt + kq);
                As[(kq + 0) * 128 + m] = v.x;
                As[(kq + 1) * 128 + m] = v.y;
                As[(kq + 2) * 128 + m] = v.z;
                As[(kq + 3) * 128 + m] = v.w;
            }
            #pragma unroll
            for (int i = 0; i < 4; ++i) {
                const int f  = t + 256 * i;
                const int k  = f >> 5;
                const int n4 = (f & 31) * 4;
                *reinterpret_cast<float4*>(Bs + k * 128 + n4) =
                    *reinterpret_cast<const float4*>(W1 + (size_t)(kt + k) * kH + hBase + n4);
            }
            __syncthreads();
            #pragma unroll 8
            for (int k = 0; k < 32; ++k) {
                const float4 a0 = *reinterpret_cast<const float4*>(As + k * 128 + r0);
                const float4 a1 = *reinterpret_cast<const float4*>(As + k * 128 + r0 + 4);
                const float4 b0 = *reinterpret_cast<const float4*>(Bs + k * 128 + c0);
                const float4 b1v = *reinterpret_cast<const float4*>(Bs + k * 128 + c0 + 4);
                const float a[8] = {a0.x, a0.y, a0.z, a0.w, a1.x, a1.y, a1.z, a1.w};
                const float b[8] = {b0.x, b0.y, b0.z, b0.w, b1v.x, b1v.y, b1v.z, b1v.w};
                #pragma unroll
                for (int i = 0; i < 8; ++i)
                    #pragma unroll
                    for (int j = 0; j < 8; ++j)
                        C[i][j] = fmaf(a[i], b[j], C[i][j]);
            }
        }

        #pragma unroll
        for (int j = 0; j < 8; ++j) {
            const float bb = b1[hBase + c0 + j];
            #pragma unroll
            for (int i = 0; i < 8; ++i) {
                const float hv = C[i][j] + bb;
                C[i][j] = 0.5f * hv * (1.0f + erff(hv * 0.70710678118654752f));
            }
        }

        for (int half = 0; half < 2; ++half) {
            __syncthreads();
            if ((tx >> 3) == half) {
                const int hloc0 = c0 - half * 64;
                #pragma unroll
                for (int j = 0; j < 8; ++j) {
                    const float4 col = make_float4(C[0][j], C[1][j], C[2][j], C[3][j]);
                    const float4 col2 = make_float4(C[4][j], C[5][j], C[6][j], C[7][j]);
                    *reinterpret_cast<float4*>(gS + (hloc0 + j) * GS_STRIDE + r0)     = col;
                    *reinterpret_cast<float4*>(gS + (hloc0 + j) * GS_STRIDE + r0 + 4) = col2;
                }
            }
            __syncthreads();
            const float* W2p = W2 + (size_t)(hBase + half * 64) * kE + g_e0;
            #pragma unroll 4
            for (int h = 0; h < 64; ++h) {
                const float4 gv = *reinterpret_cast<const float4*>(gS + h * GS_STRIDE + g_r0);
                const float4 w0 = *reinterpret_cast<const float4*>(W2p + (size_t)h * kE);
                const float4 w1 = *reinterpret_cast<const float4*>(W2p + (size_t)h * kE + 4);
                const float ga[4] = {gv.x, gv.y, gv.z, gv.w};
                const float wb[8] = {w0.x, w0.y, w0.z, w0.w, w1.x, w1.y, w1.z, w1.w};
                #pragma unroll
                for (int i = 0; i < 4; ++i)
                    #pragma unroll
                    for (int j = 0; j < 8; ++j)
                        lacc[i][j] = fmaf(ga[i], wb[j], lacc[i][j]);
            }
        }
    }

    #pragma unroll
    for (int i = 0; i < 4; ++i)
        #pragma unroll
        for (int j = 0; j < 8; ++j)
            atomicAdd(logits + (size_t)(rowBase + g_r0 + i) * kE + g_e0 + j, lacc[i][j]);
}

// ---------------------------------------------------------------------------
// Router: softmax + shared split + top-2 (min-index tie-break), idx as float
// ---------------------------------------------------------------------------
__global__ __launch_bounds__(256)
void router_kernel(const float* __restrict__ b2, float* __restrict__ out)
{
    const int lane = threadIdx.x & 63;
    const int row  = blockIdx.x * 4 + (threadIdx.x >> 6);

    float* wrow = out + OFF_W + (size_t)row * kE;
    const float logit = wrow[lane] + b2[lane];

    float m = logit;
    #pragma unroll
    for (int off = 32; off > 0; off >>= 1) m = fmaxf(m, __shfl_xor(m, off));
    const float p = expf(logit - m);
    float s = p;
    #pragma unroll
    for (int off = 32; off > 0; off >>= 1) s += __shfl_xor(s, off);
    const float w = p / s;

    wrow[lane] = w;
    if (lane < kShared) out[OFF_GW + (size_t)row * kShared + lane] = w;

    float v1 = (lane >= kShared) ? w : -1.0f;
    int   i1 = lane - kShared;
    #pragma unroll
    for (int off = 32; off > 0; off >>= 1) {
        const float ov = __shfl_xor(v1, off);
        const int   oi = __shfl_xor(i1, off);
        if (ov > v1 || (ov == v1 && oi < i1)) { v1 = ov; i1 = oi; }
    }
    float v2 = (lane >= kShared && (lane - kShared) != i1) ? w : -1.0f;
    int   i2 = lane - kShared;
    #pragma unroll
    for (int off = 32; off > 0; off >>= 1) {
        const float ov = __shfl_xor(v2, off);
        const int   oi = __shfl_xor(i2, off);
        if (ov > v2 || (ov == v2 && oi < i2)) { v2 = ov; i2 = oi; }
    }
    if (lane == 0) {
        out[OFF_LW + (size_t)row * 2 + 0] = v1;
        out[OFF_LW + (size_t)row * 2 + 1] = v2;
        out[OFF_LI + (size_t)row * 2 + 0] = (float)i1;
        out[OFF_LI + (size_t)row * 2 + 1] = (float)i2;
    }
}

extern "C" void kernel_launch(void* const* d_in, const int* in_sizes, int n_in,
                              void* d_out, int out_size, void* d_ws, size_t ws_size,
                              hipStream_t stream)
{
    const float* x  = (const float*)d_in[0];
    const float* W1 = (const float*)d_in[1];
    const float* b1 = (const float*)d_in[2];
    const float* W2 = (const float*)d_in[3];
    const float* b2 = (const float*)d_in[4];
    float* out = (float*)d_out;
    float* logits = out + OFF_W;

    hipMemsetAsync(logits, 0, (size_t)kN * kE * sizeof(float), stream);

    if (ws_size >= WS_NEEDED) {
        _Float16* base = (_Float16*)d_ws;
        hipLaunchKernelGGL(convert_x, dim3(kN * kD / 1024), dim3(256), 0, stream,
                           x, base + XH_OFF, base + XL_OFF);
        hipLaunchKernelGGL(convert_w1t, dim3((kD / 64) * (kH / 64)), dim3(256), 0, stream,
                           W1, base + W1TH_OFF, base + W1TL_OFF);
        hipLaunchKernelGGL(gemm1_mfma, dim3((kN / 128) * (kH / 128)), dim3(256), 0, stream,
                           base + XH_OFF, base + XL_OFF, base + W1TH_OFF, base + W1TL_OFF,
                           b1, W2, logits);
    } else {
        hipLaunchKernelGGL(gemm1_kernel, dim3((kN / 128) * 4), dim3(256), 0, stream,
                           x, W1, b1, W2, logits);
    }
    hipLaunchKernelGGL(router_kernel, dim3(kN / 4), dim3(256), 0, stream, b2, out);
}

// Round 3
// 1333.997 us; speedup vs baseline: 3.0835x; 1.3400x over previous
//
#include <hip/hip_runtime.h>
#include <math.h>

namespace {
constexpr int kN = 16384;
constexpr int kD = 2048;
constexpr int kH = 4096;
constexpr int kE = 64;
constexpr int kShared = 8;

// d_out layout (floats), reference return order
constexpr int OFF_GW = 0;                       // global_weights: N x 8
constexpr int OFF_LW = kN * kShared;            // local_weights:  N x 2
constexpr int OFF_LI = OFF_LW + kN * 2;         // local_indices:  N x 2 (as float)
constexpr int OFF_W  = OFF_LI + kN * 2;         // weights: N x 64 -- logit accumulator in atomic mode

constexpr int GS_STRIDE = 132;
constexpr int HSPLIT = 4;
constexpr int CHUNKS = 8;       // 8 x 128 = 1024 H-cols per block

// workspace layout (f16 elements from base)
constexpr size_t XH_OFF  = 0;
constexpr size_t XL_OFF  = (size_t)kN * kD;
constexpr size_t W1TH_OFF = XL_OFF + (size_t)kN * kD;
constexpr size_t W1TL_OFF = W1TH_OFF + (size_t)kH * kD;
constexpr size_t WS_BASE = (W1TL_OFF + (size_t)kH * kD) * 2;          // bytes: 167,772,160
constexpr size_t PART_FLOAT_OFF = WS_BASE / 4;                         // float index of partials
constexpr size_t WS_FULL = WS_BASE + (size_t)HSPLIT * kN * kE * 4;     // + 16.8 MB partials
}

typedef _Float16 half8  __attribute__((ext_vector_type(8)));
typedef _Float16 half4t __attribute__((ext_vector_type(4)));
typedef float    f32x16 __attribute__((ext_vector_type(16)));

__device__ __forceinline__ void async16(const _Float16* g, _Float16* l) {
    __builtin_amdgcn_global_load_lds(
        (const __attribute__((address_space(1))) void*)g,
        (__attribute__((address_space(3))) void*)l, 16, 0, 0);
}

// ---------------------------------------------------------------------------
// Pre-pass 1: x (fp32) -> xh, xl (f16 planes; xl pre-scaled by 2048)
// ---------------------------------------------------------------------------
__global__ __launch_bounds__(256)
void convert_x(const float* __restrict__ x, _Float16* __restrict__ xh,
               _Float16* __restrict__ xl)
{
    const size_t i = ((size_t)blockIdx.x * 256 + threadIdx.x) * 4;
    const float4 v = *reinterpret_cast<const float4*>(x + i);
    half4t h, l;
    const float vs[4] = {v.x, v.y, v.z, v.w};
    #pragma unroll
    for (int j = 0; j < 4; ++j) {
        const _Float16 hj = (_Float16)vs[j];
        h[j] = hj;
        l[j] = (_Float16)((vs[j] - (float)hj) * 2048.0f);
    }
    *reinterpret_cast<half4t*>(xh + i) = h;
    *reinterpret_cast<half4t*>(xl + i) = l;
}

// ---------------------------------------------------------------------------
// Pre-pass 2: W1 [D][H] fp32 -> W1^T hi/lo planes [H][D] f16 (lo scaled 2048)
// ---------------------------------------------------------------------------
__global__ __launch_bounds__(256)
void convert_w1t(const float* __restrict__ W1, _Float16* __restrict__ th,
                 _Float16* __restrict__ tl)
{
    __shared__ float T[64][65];
    const int bk = blockIdx.x & 31;
    const int bn = blockIdx.x >> 5;
    const int k0 = bk * 64, n0 = bn * 64;
    const int t = threadIdx.x;
    const int c4 = (t & 15) * 4, r = t >> 4;

    #pragma unroll
    for (int i = 0; i < 4; ++i) {
        const int kk = r + 16 * i;
        const float4 v = *reinterpret_cast<const float4*>(
            W1 + (size_t)(k0 + kk) * kH + n0 + c4);
        T[kk][c4 + 0] = v.x; T[kk][c4 + 1] = v.y;
        T[kk][c4 + 2] = v.z; T[kk][c4 + 3] = v.w;
    }
    __syncthreads();
    #pragma unroll
    for (int i = 0; i < 4; ++i) {
        const int nn = r + 16 * i;
        half4t h, l;
        #pragma unroll
        for (int j = 0; j < 4; ++j) {
            const float vv = T[c4 + j][nn];
            const _Float16 hj = (_Float16)vv;
            h[j] = hj;
            l[j] = (_Float16)((vv - (float)hj) * 2048.0f);
        }
        *reinterpret_cast<half4t*>(th + (size_t)(n0 + nn) * kD + k0 + c4) = h;
        *reinterpret_cast<half4t*>(tl + (size_t)(n0 + nn) * kD + k0 + c4) = l;
    }
}

// ---------------------------------------------------------------------------
// GEMM1 split-f16 3-pass MFMA, fused gelu + GEMM2 partial.
// grid = 512 (hSplit = bx&3 -> per-XCD W1 locality), block = 256 (4 waves).
// Each block: 128 rows x 1024 H-cols (8 chunks of 128), logits partial for
// its hSplit written non-atomically to ws partials (mode 0) or atomically
// into the logits region (mode 1).
// LDS staging uses source-permuted chunks: logical chunk q of row r lives at
// physical chunk q ^ (r&3) ^ ((r>>2)&3)  -> ds_read_b128 start banks spread
// over all 8 residues (was 8-way conflict, now ~2-way).
// ---------------------------------------------------------------------------
__global__ __launch_bounds__(256, 2)
void gemm1_mfma(const _Float16* __restrict__ xh, const float* __restrict__ b1,
                const float* __restrict__ W2, float* __restrict__ dst,
                int atomicMode)
{
    __shared__ __align__(16) float smem[64 * GS_STRIDE];
    _Float16* lds = (_Float16*)smem;
    float* gS = smem;

    const int t = threadIdx.x;
    const int lane = t & 63;
    const int w = t >> 6;
    const int bx = blockIdx.x;
    const int hSplit = bx & 3;          // bx%8 in {s, s+4}: each XCD serves 1 hSplit
    const int rowBlock = bx >> 2;
    const int rowBase = rowBlock * 128;

    const int mw = (w >> 1) * 64, nw = (w & 1) * 64;

    // --- staging source offsets (f16 elements rel. to xh), source-permuted
    unsigned int gofsA[4], gofsB[4];
    #pragma unroll
    for (int i = 0; i < 8; ++i) {
        const int c = i * 256 + t;          // slot 0..2047 (16 B each)
        const int tile = c >> 9;            // 0:Ah 1:Al 2:Bh 3:Bl
        const int s = c & 511;
        const int row = s >> 2;
        const int pq = s & 3;
        const int q = pq ^ (row & 3) ^ ((row >> 2) & 3);
        const unsigned int plane =
            (tile == 0) ? (unsigned int)XH_OFF :
            (tile == 1) ? (unsigned int)XL_OFF :
            (tile == 2) ? (unsigned int)W1TH_OFF : (unsigned int)W1TL_OFF;
        if (tile < 2)
            gofsA[i] = plane + (unsigned int)(rowBase + row) * kD + q * 8;
        else
            gofsB[i - 4] = plane + (unsigned int)row * kD + q * 8;
    }

    // --- frag LDS offsets (f16 elements), swizzle-aware, kt-invariant
    int aOff[2][2], bOff[2][2];
    #pragma unroll
    for (int mt = 0; mt < 2; ++mt)
        #pragma unroll
        for (int ks = 0; ks < 2; ++ks) {
            const int row = mw + mt * 32 + (lane & 31);
            const int q = (lane >> 5) + 2 * ks;
            aOff[mt][ks] = row * 32 + ((q ^ (row & 3) ^ ((row >> 2) & 3)) * 8);
        }
    #pragma unroll
    for (int nt = 0; nt < 2; ++nt)
        #pragma unroll
        for (int ks = 0; ks < 2; ++ks) {
            const int row = nw + nt * 32 + (lane & 31);
            const int q = (lane >> 5) + 2 * ks;
            bOff[nt][ks] = row * 32 + ((q ^ (row & 3) ^ ((row >> 2) & 3)) * 8);
        }

    // --- GEMM2 partial accumulators (4 rows x 8 experts per thread)
    const int g_r0 = (t >> 3) * 4;
    const int g_e0 = (t & 7) * 8;
    float lacc[4][8];
    #pragma unroll
    for (int i = 0; i < 4; ++i)
        #pragma unroll
        for (int j = 0; j < 8; ++j) lacc[i][j] = 0.0f;

    for (int chunk = 0; chunk < CHUNKS; ++chunk) {
        const int hBase = hSplit * (CHUNKS * 128) + chunk * 128;
        const unsigned int hOff = (unsigned int)hBase * kD;

        f32x16 accH[2][2], accL[2][2];
        #pragma unroll
        for (int a = 0; a < 2; ++a)
            #pragma unroll
            for (int b = 0; b < 2; ++b)
                #pragma unroll
                for (int r = 0; r < 16; ++r) { accH[a][b][r] = 0.0f; accL[a][b][r] = 0.0f; }

        for (int kt = 0; kt < kD; kt += 32) {
            __syncthreads();
            #pragma unroll
            for (int i = 0; i < 4; ++i)
                async16(xh + gofsA[i] + kt, lds + ((i * 256 + t) * 8));
            #pragma unroll
            for (int i = 0; i < 4; ++i)
                async16(xh + gofsB[i] + hOff + kt, lds + (((i + 4) * 256 + t) * 8));
            __syncthreads();

            half8 aH[2][2], aL[2][2], bH[2][2], bL[2][2];
            #pragma unroll
            for (int mt = 0; mt < 2; ++mt)
                #pragma unroll
                for (int ks = 0; ks < 2; ++ks) {
                    aH[mt][ks] = *reinterpret_cast<const half8*>(lds + aOff[mt][ks]);
                    aL[mt][ks] = *reinterpret_cast<const half8*>(lds + 4096 + aOff[mt][ks]);
                }
            #pragma unroll
            for (int nt = 0; nt < 2; ++nt)
                #pragma unroll
                for (int ks = 0; ks < 2; ++ks) {
                    bH[nt][ks] = *reinterpret_cast<const half8*>(lds + 8192 + bOff[nt][ks]);
                    bL[nt][ks] = *reinterpret_cast<const half8*>(lds + 12288 + bOff[nt][ks]);
                }

            #pragma unroll
            for (int ks = 0; ks < 2; ++ks)
                #pragma unroll
                for (int mt = 0; mt < 2; ++mt)
                    #pragma unroll
                    for (int nt = 0; nt < 2; ++nt) {
                        accH[mt][nt] = __builtin_amdgcn_mfma_f32_32x32x16_f16(
                            aH[mt][ks], bH[nt][ks], accH[mt][nt], 0, 0, 0);
                        accL[mt][nt] = __builtin_amdgcn_mfma_f32_32x32x16_f16(
                            aH[mt][ks], bL[nt][ks], accL[mt][nt], 0, 0, 0);
                        accL[mt][nt] = __builtin_amdgcn_mfma_f32_32x32x16_f16(
                            aL[mt][ks], bH[nt][ks], accL[mt][nt], 0, 0, 0);
                    }
        }

        // --- epilogue: combine + bias + gelu -> gS (g^T), GEMM2 partial
        const float inv2048 = 1.0f / 2048.0f;
        for (int hf = 0; hf < 2; ++hf) {
            __syncthreads();
            if ((w & 1) == hf) {
                #pragma unroll
                for (int nt = 0; nt < 2; ++nt) {
                    const int hl = nt * 32 + (lane & 31);
                    const float bb = b1[hBase + hf * 64 + hl];
                    #pragma unroll
                    for (int mt = 0; mt < 2; ++mt) {
                        #pragma unroll
                        for (int rq = 0; rq < 4; ++rq) {
                            float vr[4];
                            #pragma unroll
                            for (int rr = 0; rr < 4; ++rr) {
                                const int r = rq * 4 + rr;
                                const float hv = accH[mt][nt][r] + accL[mt][nt][r] * inv2048 + bb;
                                vr[rr] = 0.5f * hv * (1.0f + erff(hv * 0.70710678118654752f));
                            }
                            const int mrow = mw + mt * 32 + 8 * rq + 4 * (lane >> 5);
                            *reinterpret_cast<float4*>(gS + hl * GS_STRIDE + mrow) =
                                make_float4(vr[0], vr[1], vr[2], vr[3]);
                        }
                    }
                }
            }
            __syncthreads();
            const float* W2p = W2 + (size_t)(hBase + hf * 64) * kE + g_e0;
            #pragma unroll 4
            for (int h = 0; h < 64; ++h) {
                const float4 gv = *reinterpret_cast<const float4*>(gS + h * GS_STRIDE + g_r0);
                const float4 w0 = *reinterpret_cast<const float4*>(W2p + (size_t)h * kE);
                const float4 w1 = *reinterpret_cast<const float4*>(W2p + (size_t)h * kE + 4);
                const float ga[4] = {gv.x, gv.y, gv.z, gv.w};
                const float wb[8] = {w0.x, w0.y, w0.z, w0.w, w1.x, w1.y, w1.z, w1.w};
                #pragma unroll
                for (int i = 0; i < 4; ++i)
                    #pragma unroll
                    for (int j = 0; j < 8; ++j)
                        lacc[i][j] = fmaf(ga[i], wb[j], lacc[i][j]);
            }
        }
    }

    // --- write GEMM2 partial: exclusive slice (mode 0) or atomics (mode 1)
    if (atomicMode) {
        #pragma unroll
        for (int i = 0; i < 4; ++i)
            #pragma unroll
            for (int j = 0; j < 8; ++j)
                atomicAdd(dst + (size_t)(rowBase + g_r0 + i) * kE + g_e0 + j, lacc[i][j]);
    } else {
        float* drow = dst + ((size_t)hSplit * kN + rowBase + g_r0) * kE + g_e0;
        #pragma unroll
        for (int i = 0; i < 4; ++i) {
            *reinterpret_cast<float4*>(drow + (size_t)i * kE) =
                make_float4(lacc[i][0], lacc[i][1], lacc[i][2], lacc[i][3]);
            *reinterpret_cast<float4*>(drow + (size_t)i * kE + 4) =
                make_float4(lacc[i][4], lacc[i][5], lacc[i][6], lacc[i][7]);
        }
    }
}

// ---------------------------------------------------------------------------
// Fallback fp32 GEMM1 (verified R1 kernel) — used when ws is too small
// ---------------------------------------------------------------------------
__global__ __launch_bounds__(256, 2)
void gemm1_kernel(const float* __restrict__ x, const float* __restrict__ W1,
                  const float* __restrict__ b1, const float* __restrict__ W2,
                  float* __restrict__ logits)
{
    __shared__ __align__(16) float smem[64 * GS_STRIDE];
    float* As = smem;
    float* Bs = smem + 32 * 128;
    float* gS = smem;

    const int t  = threadIdx.x;
    const int bx = blockIdx.x;
    const int rowBlock = bx >> 2;
    const int hSplit   = bx & 3;
    const int rowBase  = rowBlock * 128;
    const int hBase0   = hSplit * 1024;

    const int ty = t >> 4;
    const int tx = t & 15;
    const int r0 = ty * 8;
    const int c0 = tx * 8;
    const int g_r0 = (t >> 3) * 4;
    const int g_e0 = (t & 7) * 8;

    float lacc[4][8];
    #pragma unroll
    for (int i = 0; i < 4; ++i)
        #pragma unroll
        for (int j = 0; j < 8; ++j) lacc[i][j] = 0.0f;

    for (int chunk = 0; chunk < 8; ++chunk) {
        const int hBase = hBase0 + chunk * 128;
        float C[8][8];
        #pragma unroll
        for (int i = 0; i < 8; ++i)
            #pragma unroll
            for (int j = 0; j < 8; ++j) C[i][j] = 0.0f;

        for (int kt = 0; kt < kD; kt += 32) {
            __syncthreads();
            #pragma unroll
            for (int i = 0; i < 4; ++i) {
                const int f  = t + 256 * i;
                const int m  = f >> 3;
                const int kq = (f & 7) * 4;
                const float4 v = *reinterpret_cast<const float4*>(
                    x + (size_t)(rowBase + m) * kD + kt + kq);
                As[(kq + 0) * 128 + m] = v.x;
                As[(kq + 1) * 128 + m] = v.y;
                As[(kq + 2) * 128 + m] = v.z;
                As[(kq + 3) * 128 + m] = v.w;
            }
            #pragma unroll
            for (int i = 0; i < 4; ++i) {
                const int f  = t + 256 * i;
                const int k  = f >> 5;
                const int n4 = (f & 31) * 4;
                *reinterpret_cast<float4*>(Bs + k * 128 + n4) =
                    *reinterpret_cast<const float4*>(W1 + (size_t)(kt + k) * kH + hBase + n4);
            }
            __syncthreads();
            #pragma unroll 8
            for (int k = 0; k < 32; ++k) {
                const float4 a0 = *reinterpret_cast<const float4*>(As + k * 128 + r0);
                const float4 a1 = *reinterpret_cast<const float4*>(As + k * 128 + r0 + 4);
                const float4 b0 = *reinterpret_cast<const float4*>(Bs + k * 128 + c0);
                const float4 b1v = *reinterpret_cast<const float4*>(Bs + k * 128 + c0 + 4);
                const float a[8] = {a0.x, a0.y, a0.z, a0.w, a1.x, a1.y, a1.z, a1.w};
                const float b[8] = {b0.x, b0.y, b0.z, b0.w, b1v.x, b1v.y, b1v.z, b1v.w};
                #pragma unroll
                for (int i = 0; i < 8; ++i)
                    #pragma unroll
                    for (int j = 0; j < 8; ++j)
                        C[i][j] = fmaf(a[i], b[j], C[i][j]);
            }
        }

        #pragma unroll
        for (int j = 0; j < 8; ++j) {
            const float bb = b1[hBase + c0 + j];
            #pragma unroll
            for (int i = 0; i < 8; ++i) {
                const float hv = C[i][j] + bb;
                C[i][j] = 0.5f * hv * (1.0f + erff(hv * 0.70710678118654752f));
            }
        }

        for (int half = 0; half < 2; ++half) {
            __syncthreads();
            if ((tx >> 3) == half) {
                const int hloc0 = c0 - half * 64;
                #pragma unroll
                for (int j = 0; j < 8; ++j) {
                    const float4 col = make_float4(C[0][j], C[1][j], C[2][j], C[3][j]);
                    const float4 col2 = make_float4(C[4][j], C[5][j], C[6][j], C[7][j]);
                    *reinterpret_cast<float4*>(gS + (hloc0 + j) * GS_STRIDE + r0)     = col;
                    *reinterpret_cast<float4*>(gS + (hloc0 + j) * GS_STRIDE + r0 + 4) = col2;
                }
            }
            __syncthreads();
            const float* W2p = W2 + (size_t)(hBase + half * 64) * kE + g_e0;
            #pragma unroll 4
            for (int h = 0; h < 64; ++h) {
                const float4 gv = *reinterpret_cast<const float4*>(gS + h * GS_STRIDE + g_r0);
                const float4 w0 = *reinterpret_cast<const float4*>(W2p + (size_t)h * kE);
                const float4 w1 = *reinterpret_cast<const float4*>(W2p + (size_t)h * kE + 4);
                const float ga[4] = {gv.x, gv.y, gv.z, gv.w};
                const float wb[8] = {w0.x, w0.y, w0.z, w0.w, w1.x, w1.y, w1.z, w1.w};
                #pragma unroll
                for (int i = 0; i < 4; ++i)
                    #pragma unroll
                    for (int j = 0; j < 8; ++j)
                        lacc[i][j] = fmaf(ga[i], wb[j], lacc[i][j]);
            }
        }
    }

    #pragma unroll
    for (int i = 0; i < 4; ++i)
        #pragma unroll
        for (int j = 0; j < 8; ++j)
            atomicAdd(logits + (size_t)(rowBase + g_r0 + i) * kE + g_e0 + j, lacc[i][j]);
}

// ---------------------------------------------------------------------------
// Router: logits from partials (mode 0) or logits buffer (mode 1); softmax,
// shared split, top-2 with min-index tie-break, indices written as float.
// ---------------------------------------------------------------------------
__global__ __launch_bounds__(256)
void router_kernel(const float* __restrict__ b2, const float* __restrict__ src,
                   int atomicMode, float* __restrict__ out)
{
    const int lane = threadIdx.x & 63;
    const int row  = blockIdx.x * 4 + (threadIdx.x >> 6);

    float logit;
    if (atomicMode) {
        logit = src[(size_t)row * kE + lane] + b2[lane];
    } else {
        const float* p = src + (size_t)row * kE + lane;
        logit = p[0] + p[(size_t)kN * kE] + p[(size_t)2 * kN * kE] +
                p[(size_t)3 * kN * kE] + b2[lane];
    }

    float m = logit;
    #pragma unroll
    for (int off = 32; off > 0; off >>= 1) m = fmaxf(m, __shfl_xor(m, off));
    const float p = expf(logit - m);
    float s = p;
    #pragma unroll
    for (int off = 32; off > 0; off >>= 1) s += __shfl_xor(s, off);
    const float w = p / s;

    out[OFF_W + (size_t)row * kE + lane] = w;
    if (lane < kShared) out[OFF_GW + (size_t)row * kShared + lane] = w;

    float v1 = (lane >= kShared) ? w : -1.0f;
    int   i1 = lane - kShared;
    #pragma unroll
    for (int off = 32; off > 0; off >>= 1) {
        const float ov = __shfl_xor(v1, off);
        const int   oi = __shfl_xor(i1, off);
        if (ov > v1 || (ov == v1 && oi < i1)) { v1 = ov; i1 = oi; }
    }
    float v2 = (lane >= kShared && (lane - kShared) != i1) ? w : -1.0f;
    int   i2 = lane - kShared;
    #pragma unroll
    for (int off = 32; off > 0; off >>= 1) {
        const float ov = __shfl_xor(v2, off);
        const int   oi = __shfl_xor(i2, off);
        if (ov > v2 || (ov == v2 && oi < i2)) { v2 = ov; i2 = oi; }
    }
    if (lane == 0) {
        out[OFF_LW + (size_t)row * 2 + 0] = v1;
        out[OFF_LW + (size_t)row * 2 + 1] = v2;
        out[OFF_LI + (size_t)row * 2 + 0] = (float)i1;
        out[OFF_LI + (size_t)row * 2 + 1] = (float)i2;
    }
}

extern "C" void kernel_launch(void* const* d_in, const int* in_sizes, int n_in,
                              void* d_out, int out_size, void* d_ws, size_t ws_size,
                              hipStream_t stream)
{
    const float* x  = (const float*)d_in[0];
    const float* W1 = (const float*)d_in[1];
    const float* b1 = (const float*)d_in[2];
    const float* W2 = (const float*)d_in[3];
    const float* b2 = (const float*)d_in[4];
    float* out = (float*)d_out;
    float* logits = out + OFF_W;

    if (ws_size >= WS_BASE) {
        _Float16* base = (_Float16*)d_ws;
        const int atomicMode = (ws_size >= WS_FULL) ? 0 : 1;
        float* dst = atomicMode ? logits : ((float*)d_ws + PART_FLOAT_OFF);
        if (atomicMode)
            hipMemsetAsync(logits, 0, (size_t)kN * kE * sizeof(float), stream);
        hipLaunchKernelGGL(convert_x, dim3(kN * kD / 1024), dim3(256), 0, stream,
                           x, base + XH_OFF, base + XL_OFF);
        hipLaunchKernelGGL(convert_w1t, dim3((kD / 64) * (kH / 64)), dim3(256), 0, stream,
                           W1, base + W1TH_OFF, base + W1TL_OFF);
        hipLaunchKernelGGL(gemm1_mfma, dim3((kN / 128) * HSPLIT), dim3(256), 0, stream,
                           base + XH_OFF, b1, W2, dst, atomicMode);
        hipLaunchKernelGGL(router_kernel, dim3(kN / 4), dim3(256), 0, stream,
                           b2, dst, atomicMode, out);
    } else {
        hipMemsetAsync(logits, 0, (size_t)kN * kE * sizeof(float), stream);
        hipLaunchKernelGGL(gemm1_kernel, dim3((kN / 128) * 4), dim3(256), 0, stream,
                           x, W1, b1, W2, logits);
        hipLaunchKernelGGL(router_kernel, dim3(kN / 4), dim3(256), 0, stream,
                           b2, logits, 1, out);
    }
}